// Round 14
// baseline (471.053 us; speedup 1.0000x reference)
//
#include <hip/hip_runtime.h>
#include <hip/hip_bf16.h>
#include <stdint.h>

#define B_SZ 4
#define L_SEQ 2048
#define EMB 2048
#define NH 16
#define HD 128
#define BLROWS (B_SZ * L_SEQ)   // 8192
#define BK 32

typedef __bf16 bf16;
typedef __bf16 bf16x8 __attribute__((ext_vector_type(8)));
typedef __bf16 bf16x4 __attribute__((ext_vector_type(4)));
typedef float f32x4 __attribute__((ext_vector_type(4)));

#define MFMA16(A, Bv, C) __builtin_amdgcn_mfma_f32_16x16x32_bf16(A, Bv, C, 0, 0, 0)

__device__ __forceinline__ void gll16(bf16* l, const bf16* g) {
  __builtin_amdgcn_global_load_lds(
      (const __attribute__((address_space(1))) unsigned int*)g,
      (__attribute__((address_space(3))) unsigned int*)l, 16, 0, 0);
}

// ---------------- all fp32 -> bf16 conversions, one launch ----------------
__global__ __launch_bounds__(256) void f2bAll_kernel(
    const float* __restrict__ x, const float* __restrict__ w0,
    const float* __restrict__ w1, const float* __restrict__ w2,
    const float* __restrict__ w3, bf16* __restrict__ ox, bf16* __restrict__ o0,
    bf16* __restrict__ o1, bf16* __restrict__ o2, bf16* __restrict__ o3,
    int nx4, int nw4) {
  const int y = blockIdx.y;
  const float* in = (y == 0) ? x : (y == 1) ? w0 : (y == 2) ? w1
                    : (y == 3) ? w2 : w3;
  bf16* out = (y == 0) ? ox : (y == 1) ? o0 : (y == 2) ? o1
              : (y == 3) ? o2 : o3;
  const int n4 = (y == 0) ? nx4 : nw4;
  int i = blockIdx.x * blockDim.x + threadIdx.x;
  int stride = gridDim.x * blockDim.x;
  for (; i < n4; i += stride) {
    float4 v = ((const float4*)in)[i];
    bf16x4 o = {(bf16)v.x, (bf16)v.y, (bf16)v.z, (bf16)v.w};
    ((bf16x4*)out)[i] = o;
  }
}

// ---- QKV GEMM: 256x256, BK=64, 2-stage, ONE barrier-pair per iteration ----
// Same 2-barrier rhythm as the proven BK=32 kernel, but half the barrier /
// drain / loop-overhead events. vmcnt(0) at iter end waits loads issued at
// iter top (~600+cy of MFMA cover). Grouped raster (XCD-resident A) kept.
__global__ __launch_bounds__(512, 2) void gemmQKV64(const bf16* __restrict__ A,
                                                    const bf16* __restrict__ Bm,
                                                    bf16* __restrict__ Cq,
                                                    bf16* __restrict__ Ck,
                                                    bf16* __restrict__ Cvt,
                                                    int K) {
  __shared__ bf16 Abuf[2][256 * 64];   // 32 KB each
  __shared__ bf16 Bbuf[2][256 * 64];
  const int tid = threadIdx.x, lane = tid & 63, w = tid >> 6;
  const int wr = w >> 2, wc = w & 3;
  const int l15 = lane & 15, grp = lane >> 4;

  const int bx = blockIdx.x;
  const int bm = ((bx & 7) * 4 + ((bx >> 3) & 3)) * 256;
  const int bn = (bx >> 5) * 256;
  const int NT = K >> 6;   // 32

  // staging: 4 glls each for A and B; chunk id = g*512+tid; 8 chunks/row
  size_t sAg[4], sBg[4];
  int sdst[4];
#pragma unroll
  for (int g = 0; g < 4; g++) {
    int id = g * 512 + tid;
    int row = id >> 3, c = id & 7;
    int scol = (c ^ (row & 7)) * 8;
    sAg[g] = (size_t)(bm + row) * K + scol;
    sBg[g] = (size_t)(bn + row) * K + scol;
    sdst[g] = id * 8;
  }

  // fragment read offsets (swizzled, 128B rows): verified r5/r7, 0 conflicts
  int aoff[8][2], boff[4][2];
#pragma unroll
  for (int m = 0; m < 8; m++)
#pragma unroll
    for (int ks = 0; ks < 2; ks++) {
      int row = wr * 128 + m * 16 + l15;
      int cl = ks * 4 + grp;
      aoff[m][ks] = row * 64 + ((cl ^ (row & 7)) * 8);
    }
#pragma unroll
  for (int n = 0; n < 4; n++)
#pragma unroll
    for (int ks = 0; ks < 2; ks++) {
      int row = wc * 64 + n * 16 + l15;
      int cl = ks * 4 + grp;
      boff[n][ks] = row * 64 + ((cl ^ (row & 7)) * 8);
    }

  f32x4 acc[8][4] = {};

  // prologue: stage tile 0
#pragma unroll
  for (int g = 0; g < 4; g++) {
    gll16(&Abuf[0][sdst[g]], A + sAg[g]);
    gll16(&Bbuf[0][sdst[g]], Bm + sBg[g]);
  }
  asm volatile("s_waitcnt vmcnt(0)" ::: "memory");
  __builtin_amdgcn_s_barrier();
  asm volatile("" ::: "memory");

  for (int t = 0; t < NT; ++t) {
    const bf16* __restrict__ Ab = Abuf[t & 1];
    const bf16* __restrict__ Bb = Bbuf[t & 1];
    bf16* __restrict__ An = Abuf[(t + 1) & 1];
    bf16* __restrict__ Bn = Bbuf[(t + 1) & 1];
    const size_t k1 = (size_t)(t + 1) << 6;
    const bool pre = (t + 1 < NT);

    // issue next-tile staging first (max issue-to-wait distance)
    if (pre) {
#pragma unroll
      for (int g = 0; g < 4; g++) {
        gll16(&An[sdst[g]], A + sAg[g] + k1);
        gll16(&Bn[sdst[g]], Bm + sBg[g] + k1);
      }
    }

#pragma unroll
    for (int ks = 0; ks < 2; ks++) {
      bf16x8 af[8], bq[4];
#pragma unroll
      for (int m = 0; m < 8; m++) af[m] = *(const bf16x8*)&Ab[aoff[m][ks]];
#pragma unroll
      for (int n = 0; n < 4; n++) bq[n] = *(const bf16x8*)&Bb[boff[n][ks]];
      asm volatile("s_waitcnt lgkmcnt(0)" ::: "memory");
      __builtin_amdgcn_sched_barrier(0);
      __builtin_amdgcn_s_setprio(1);
#pragma unroll
      for (int n = 0; n < 4; n++)
#pragma unroll
        for (int m = 0; m < 8; m++)
          acc[m][n] = MFMA16(af[m], bq[n], acc[m][n]);
      __builtin_amdgcn_s_setprio(0);
    }

    if (t < NT - 1) {
      asm volatile("s_waitcnt vmcnt(0)" ::: "memory");
      __builtin_amdgcn_s_barrier();
      asm volatile("" ::: "memory");
    }
  }

  // epilogue: fused QKV routing (Q,K row-major bf16; V transposed per batch)
  const int grow0 = bm + wr * 128 + grp * 4;
  const int gcol0 = bn + wc * 64 + l15;
#pragma unroll
  for (int i = 0; i < 8; i++)
#pragma unroll
    for (int j = 0; j < 4; j++) {
      int grow = grow0 + i * 16;
      int gcol = gcol0 + j * 16;
      int mat = gcol >> 11, mcol = gcol & 2047;
      if (mat == 2) {
        int b = grow >> 11;
        bf16x4 pk = {(bf16)acc[i][j][0], (bf16)acc[i][j][1],
                     (bf16)acc[i][j][2], (bf16)acc[i][j][3]};
        *(bf16x4*)&Cvt[((size_t)(b * 2048 + mcol)) * 2048 + (grow & 2047)] = pk;
      } else {
        bf16* Cp = (mat == 0) ? Cq : Ck;
#pragma unroll
        for (int r = 0; r < 4; r++)
          Cp[(size_t)(grow + r) * 2048 + mcol] = (bf16)acc[i][j][r];
      }
    }
}

// ------- out-proj GEMM: 256x128, BK=32, 3-stage counted-vmcnt (proven) -----
__global__ __launch_bounds__(512, 2) void gemmOut(const bf16* __restrict__ A,
                                                  const bf16* __restrict__ Bm,
                                                  float* __restrict__ Cf,
                                                  int K) {
  constexpr int BNT = 128, NB = 2;
  __shared__ bf16 Abuf[3][256 * BK];
  __shared__ bf16 Bbuf[3][BNT * BK];
  const int tid = threadIdx.x, lane = tid & 63, w = tid >> 6;
  const int wr = w >> 2, wc = w & 3;
  const int l15 = lane & 15;

  const int bx = blockIdx.x;
  const int bm = ((bx & 7) * 4 + ((bx >> 3) & 3)) * 256;
  const int bn = (bx >> 5) * BNT;
  const int NT = K / BK;

  const int idA0 = tid, idA1 = 512 + tid;
  const int ar0 = idA0 >> 2, ar1 = idA1 >> 2;
  const size_t aS0 = (size_t)(bm + ar0) * K + (((idA0 & 3) ^ ((ar0 >> 1) & 3)) * 8);
  const size_t aS1 = (size_t)(bm + ar1) * K + (((idA1 & 3) ^ ((ar1 >> 1) & 3)) * 8);
  const size_t bS0 = (size_t)(bn + ar0) * K + (((idA0 & 3) ^ ((ar0 >> 1) & 3)) * 8);
  const int ldsD0 = idA0 * 8, ldsD1 = idA1 * 8;

  const int eSw = ((lane >> 4) * 8) ^ (((l15 >> 1) & 3) << 3);
  int aoff[8], boff[NB];
#pragma unroll
  for (int m = 0; m < 8; m++) aoff[m] = (wr * 128 + m * 16 + l15) * BK + eSw;
#pragma unroll
  for (int n = 0; n < NB; n++) boff[n] = (wc * (BNT / 4) + n * 16 + l15) * BK + eSw;

  f32x4 acc[8][NB] = {};

  gll16(&Abuf[0][ldsD0], A + aS0);
  gll16(&Bbuf[0][ldsD0], Bm + bS0);
  gll16(&Abuf[0][ldsD1], A + aS1);
  gll16(&Abuf[1][ldsD0], A + aS0 + BK);
  gll16(&Bbuf[1][ldsD0], Bm + bS0 + BK);
  gll16(&Abuf[1][ldsD1], A + aS1 + BK);
  asm volatile("s_waitcnt vmcnt(3)" ::: "memory");
  __builtin_amdgcn_s_barrier();
  asm volatile("" ::: "memory");

  int cur = 0, nxt = 2;
  for (int kt = 0; kt < NT; ++kt) {
    const bf16* __restrict__ Ab = Abuf[cur];
    const bf16* __restrict__ Bb = Bbuf[cur];
    const bool pre = (kt + 2 < NT);
    const size_t k2 = (size_t)(kt + 2) * BK;

    bf16x8 af[8], bq[NB];
#pragma unroll
    for (int m = 0; m < 8; m++) af[m] = *(const bf16x8*)&Ab[aoff[m]];
    bq[0] = *(const bf16x8*)&Bb[boff[0]];
    if (pre) {
      gll16(&Abuf[nxt][ldsD0], A + aS0 + k2);
      gll16(&Bbuf[nxt][ldsD0], Bm + bS0 + k2);
    }
    asm volatile("s_waitcnt lgkmcnt(0)" ::: "memory");
    __builtin_amdgcn_sched_barrier(0);
    __builtin_amdgcn_s_setprio(1);
#pragma unroll
    for (int m = 0; m < 8; m++) acc[m][0] = MFMA16(af[m], bq[0], acc[m][0]);
    __builtin_amdgcn_s_setprio(0);

    bf16x8 b2 = *(const bf16x8*)&Bb[boff[1]];
    if (pre) gll16(&Abuf[nxt][ldsD1], A + aS1 + k2);
    asm volatile("s_waitcnt lgkmcnt(0)" ::: "memory");
    __builtin_amdgcn_sched_barrier(0);
    __builtin_amdgcn_s_setprio(1);
#pragma unroll
    for (int m = 0; m < 8; m++) acc[m][1] = MFMA16(af[m], b2, acc[m][1]);
    __builtin_amdgcn_s_setprio(0);

    if (kt < NT - 1) {
      if (pre)
        asm volatile("s_waitcnt vmcnt(3)" ::: "memory");
      else
        asm volatile("s_waitcnt vmcnt(0)" ::: "memory");
      __builtin_amdgcn_s_barrier();
      asm volatile("" ::: "memory");
    }
    cur = (cur == 2) ? 0 : cur + 1;
    nxt = (nxt == 2) ? 0 : nxt + 1;
  }

  const int grow0 = bm + wr * 128 + (lane >> 4) * 4;
  const int gcol0 = bn + wc * (BNT / 4) + l15;
#pragma unroll
  for (int i = 0; i < 8; i++)
#pragma unroll
    for (int j = 0; j < NB; j++) {
      int grow = grow0 + i * 16;
      int gcol = gcol0 + j * 16;
#pragma unroll
      for (int r = 0; r < 4; r++)
        Cf[(size_t)(grow + r) * 2048 + gcol] = acc[i][j][r];
    }
}

// ---------------- fused RMSNorm + RoPE for Q and K, one launch -------------
__global__ __launch_bounds__(256) void normrope2_kernel(bf16* __restrict__ Tq,
                                                        bf16* __restrict__ Tk,
                                                        const float* __restrict__ wq,
                                                        const float* __restrict__ wk,
                                                        const float* __restrict__ cs,
                                                        const float* __restrict__ sn) {
  bf16* T = blockIdx.y ? Tk : Tq;
  const float* w = blockIdx.y ? wk : wq;
  int row = blockIdx.x * 4 + (threadIdx.x >> 6);
  int lane = threadIdx.x & 63;
  int bl = row >> 4;
  int h = row & 15;
  bf16* p = T + (size_t)bl * EMB + h * HD;
  float v1 = (float)p[lane];
  float v2 = (float)p[lane + 64];
  float ss = v1 * v1 + v2 * v2;
#pragma unroll
  for (int m = 32; m; m >>= 1) ss += __shfl_xor(ss, m, 64);
  float r = rsqrtf(ss * (1.0f / 128.0f) + 1e-6f);
  float n1 = v1 * r * w[lane];
  float n2 = v2 * r * w[lane + 64];
  float c = cs[(size_t)bl * 64 + lane];
  float s = sn[(size_t)bl * 64 + lane];
  p[lane]      = (bf16)(n1 * c - n2 * s);
  p[lane + 64] = (bf16)(n1 * s + n2 * c);
}

// ---------------- causal flash attention (round-4 proven version) ----------
__device__ __forceinline__ void stage_kv(bf16* Ksb, bf16* Vsb,
                                         const bf16* gK, const bf16* gV,
                                         int kt, int w, int lane) {
#pragma unroll
  for (int i = 0; i < 4; i++) {
    int ck = i * 256 + w * 64 + lane;
    int kr = ck >> 4, kc = ck & 15;
    gll16(&Ksb[ck * 8], gK + (size_t)(kt * 64 + kr) * EMB + ((kc ^ (kr & 7)) * 8));
    int dr = ck >> 3, vc = ck & 7;
    gll16(&Vsb[ck * 8], gV + (size_t)dr * L_SEQ + kt * 64 + ((vc ^ (dr & 7)) * 8));
  }
}

__global__ __launch_bounds__(256) void fattn_kernel(const bf16* __restrict__ Q,
                                                    const bf16* __restrict__ K,
                                                    const bf16* __restrict__ Vt,
                                                    bf16* __restrict__ AO) {
  __shared__ bf16 Ks[2][64 * 128];
  __shared__ bf16 Vs[2][64 * 128];
  __shared__ bf16 Ps[4 * 16 * 64];
  const int tid = threadIdx.x, lane = tid & 63, w = tid >> 6;

  int id = blockIdx.x + blockIdx.y * 32;
  int bh = id & 63;
  int qt = 31 - (id >> 6);
  const int b = bh >> 4, h = bh & 15;
  const size_t base = (size_t)b * L_SEQ * EMB + h * HD;
  const bf16* gK = K + base;
  const bf16* gV = Vt + (size_t)(b * NH + h) * HD * L_SEQ;
  const int qrow0 = qt * 64 + w * 16;

  const float a_ = 0.08838834764831845f * 1.4426950408889634f;
  const float b_ = 12.0f * 1.4426950408889634f;

  bf16x8 qf[4];
  {
    const bf16* qp = Q + base + (size_t)(qrow0 + (lane & 15)) * EMB + ((lane >> 4) * 8);
#pragma unroll
    for (int c = 0; c < 4; c++) qf[c] = *(const bf16x8*)(qp + c * 32);
  }
  const bf16 one1 = (bf16)1.0f;
  const bf16x8 ones = {one1, one1, one1, one1, one1, one1, one1, one1};

  f32x4 O[8] = {};
  f32x4 lsum = {0.f, 0.f, 0.f, 0.f};
  const int qg0 = qrow0 + (lane >> 4) * 4;
  bf16* myP = Ps + w * 1024;

  stage_kv(Ks[0], Vs[0], gK, gV, 0, w, lane);
  asm volatile("s_waitcnt vmcnt(0)" ::: "memory");
  __builtin_amdgcn_s_barrier();
  asm volatile("" ::: "memory");

  for (int kt = 0; kt <= qt; kt++) {
    const int cur = kt & 1;
    if (kt < qt) stage_kv(Ks[cur ^ 1], Vs[cur ^ 1], gK, gV, kt + 1, w, lane);

    f32x4 S[4] = {};
    __builtin_amdgcn_s_setprio(1);
#pragma unroll
    for (int s = 0; s < 4; s++) {
      int row = s * 16 + (lane & 15);
#pragma unroll
      for (int c = 0; c < 4; c++) {
        int swc = (c * 4 + (lane >> 4)) ^ (row & 7);
        bf16x8 kf = *(const bf16x8*)&Ks[cur][row * 128 + swc * 8];
        S[s] = MFMA16(qf[c], kf, S[s]);
      }
    }
    __builtin_amdgcn_s_setprio(0);

    const bool diag = (kt == qt);
    const int prow = (lane >> 4) * 4;
#pragma unroll
    for (int s = 0; s < 4; s++) {
      int kg = kt * 64 + s * 16 + (lane & 15);
#pragma unroll
      for (int r = 0; r < 4; r++) {
        float e = exp2f(S[s][r] * a_ - b_);
        if (diag && kg > qg0 + r) e = 0.f;
        int row = prow + r;
        myP[(row * 64 + s * 16 + (lane & 15)) ^ ((row & 7) << 3)] = (bf16)e;
      }
    }
    bf16x8 pf[2];
#pragma unroll
    for (int kk = 0; kk < 2; kk++) {
      int row = lane & 15;
      int swc = (kk * 4 + (lane >> 4)) ^ (row & 7);
      pf[kk] = *(const bf16x8*)&myP[row * 64 + swc * 8];
    }
    __builtin_amdgcn_s_setprio(1);
    lsum = MFMA16(pf[0], ones, lsum);
    lsum = MFMA16(pf[1], ones, lsum);
#pragma unroll
    for (int ni = 0; ni < 8; ni++) {
#pragma unroll
      for (int kk = 0; kk < 2; kk++) {
        int drow = ni * 16 + (lane & 15);
        int swc = (kk * 4 + (lane >> 4)) ^ (drow & 7);
        bf16x8 vf = *(const bf16x8*)&Vs[cur][drow * 64 + swc * 8];
        O[ni] = MFMA16(pf[kk], vf, O[ni]);
      }
    }
    __builtin_amdgcn_s_setprio(0);

    asm volatile("s_waitcnt vmcnt(0)" ::: "memory");
    __builtin_amdgcn_s_barrier();
    asm volatile("" ::: "memory");
  }

#pragma unroll
  for (int ni = 0; ni < 8; ni++) {
#pragma unroll
    for (int r = 0; r < 4; r++) {
      float o = O[ni][r] / lsum[r];
      AO[(size_t)(b * L_SEQ + qg0 + r) * EMB + h * HD + ni * 16 + (lane & 15)] = (bf16)o;
    }
  }
}

extern "C" void kernel_launch(void* const* d_in, const int* in_sizes, int n_in,
                              void* d_out, int out_size, void* d_ws, size_t ws_size,
                              hipStream_t stream) {
  const float* x = (const float*)d_in[0];
  const float* cosp = (const float*)d_in[2];
  const float* sinp = (const float*)d_in[3];
  const float* Wq = (const float*)d_in[4];
  const float* Wk = (const float*)d_in[5];
  const float* Wv = (const float*)d_in[6];
  const float* Wo = (const float*)d_in[7];
  const float* qw = (const float*)d_in[8];
  const float* kw = (const float*)d_in[9];

  const size_t ACT = (size_t)BLROWS * EMB * sizeof(bf16);
  const size_t WGT = (size_t)EMB * EMB * sizeof(bf16);
  char* ws = (char*)d_ws;
  bf16* xb    = (bf16*)ws;          ws += ACT;
  bf16* WQKVb = (bf16*)ws;          ws += 3 * WGT;
  bf16* Wob   = (bf16*)ws;          ws += WGT;
  bf16* Qb    = (bf16*)ws;          ws += ACT;
  bf16* Kb    = (bf16*)ws;          ws += ACT;
  bf16* Vtb   = (bf16*)ws;          ws += ACT;
  bf16* AOb   = (bf16*)ws;          ws += ACT;

  f2bAll_kernel<<<dim3(512, 5), 256, 0, stream>>>(
      x, Wq, Wk, Wv, Wo, xb, WQKVb, WQKVb + (size_t)EMB * EMB,
      WQKVb + 2 * (size_t)EMB * EMB, Wob, BLROWS * EMB / 4, EMB * EMB / 4);

  gemmQKV64<<<768, 512, 0, stream>>>(xb, WQKVb, Qb, Kb, Vtb, EMB);

  normrope2_kernel<<<dim3(BLROWS * NH / 4, 2), 256, 0, stream>>>(Qb, Kb, qw, kw,
                                                                 cosp, sinp);

  fattn_kernel<<<dim3(32, B_SZ * NH), 256, 0, stream>>>(Qb, Kb, Vtb, AOb);

  gemmOut<<<512, 512, 0, stream>>>(AOb, Wob, (float*)d_out, EMB);
}

// Round 15
// 454.039 us; speedup vs baseline: 1.0375x; 1.0375x over previous
//
#include <hip/hip_runtime.h>
#include <hip/hip_bf16.h>
#include <stdint.h>

#define B_SZ 4
#define L_SEQ 2048
#define EMB 2048
#define NH 16
#define HD 128
#define BLROWS (B_SZ * L_SEQ)   // 8192
#define BK 32

typedef __bf16 bf16;
typedef __bf16 bf16x8 __attribute__((ext_vector_type(8)));
typedef __bf16 bf16x4 __attribute__((ext_vector_type(4)));
typedef float f32x4 __attribute__((ext_vector_type(4)));

#define MFMA16(A, Bv, C) __builtin_amdgcn_mfma_f32_16x16x32_bf16(A, Bv, C, 0, 0, 0)

__device__ __forceinline__ void gll16(bf16* l, const bf16* g) {
  __builtin_amdgcn_global_load_lds(
      (const __attribute__((address_space(1))) unsigned int*)g,
      (__attribute__((address_space(3))) unsigned int*)l, 16, 0, 0);
}

// ---------------- all fp32 -> bf16 conversions, one launch ----------------
__global__ __launch_bounds__(256) void f2bAll_kernel(
    const float* __restrict__ x, const float* __restrict__ w0,
    const float* __restrict__ w1, const float* __restrict__ w2,
    const float* __restrict__ w3, bf16* __restrict__ ox, bf16* __restrict__ o0,
    bf16* __restrict__ o1, bf16* __restrict__ o2, bf16* __restrict__ o3,
    int nx4, int nw4) {
  const int y = blockIdx.y;
  const float* in = (y == 0) ? x : (y == 1) ? w0 : (y == 2) ? w1
                    : (y == 3) ? w2 : w3;
  bf16* out = (y == 0) ? ox : (y == 1) ? o0 : (y == 2) ? o1
              : (y == 3) ? o2 : o3;
  const int n4 = (y == 0) ? nx4 : nw4;
  int i = blockIdx.x * blockDim.x + threadIdx.x;
  int stride = gridDim.x * blockDim.x;
  for (; i < n4; i += stride) {
    float4 v = ((const float4*)in)[i];
    bf16x4 o = {(bf16)v.x, (bf16)v.y, (bf16)v.z, (bf16)v.w};
    ((bf16x4*)out)[i] = o;
  }
}

// ------- 256xBNT GEMM, BK=32, 3-stage counted-vmcnt pipeline ---------------
// Grouped raster: XCD x (bx&7) owns a 4-bm x all-bn rectangle -> per-XCD A
// working set 4MB (L2-resident). (round-11/13 proven: QKV 200us, FETCH 148MB)
template <int EPI, int BNT>
__global__ __launch_bounds__(512, 2) void gemm256(const bf16* __restrict__ A,
                                                  const bf16* __restrict__ Bm,
                                                  bf16* __restrict__ Cq,
                                                  bf16* __restrict__ Ck,
                                                  bf16* __restrict__ Cvt,
                                                  float* __restrict__ Cf,
                                                  int K) {
  constexpr int NB = BNT / 64;
  __shared__ bf16 Abuf[3][256 * BK];
  __shared__ bf16 Bbuf[3][BNT * BK];
  const int tid = threadIdx.x, lane = tid & 63, w = tid >> 6;
  const int wr = w >> 2, wc = w & 3;
  const int l15 = lane & 15;

  const int bx = blockIdx.x;
  const int bm = ((bx & 7) * 4 + ((bx >> 3) & 3)) * 256;
  const int bn = (bx >> 5) * BNT;
  const int NT = K / BK;

  const int idA0 = tid, idA1 = 512 + tid;
  const int ar0 = idA0 >> 2, ar1 = idA1 >> 2;
  const size_t aS0 = (size_t)(bm + ar0) * K + (((idA0 & 3) ^ ((ar0 >> 1) & 3)) * 8);
  const size_t aS1 = (size_t)(bm + ar1) * K + (((idA1 & 3) ^ ((ar1 >> 1) & 3)) * 8);
  const size_t bS0 = (size_t)(bn + ar0) * K + (((idA0 & 3) ^ ((ar0 >> 1) & 3)) * 8);
  const size_t bS1 = (size_t)(bn + ar1) * K + (((idA1 & 3) ^ ((ar1 >> 1) & 3)) * 8);
  const int ldsD0 = idA0 * 8, ldsD1 = idA1 * 8;

  const int eSw = ((lane >> 4) * 8) ^ (((l15 >> 1) & 3) << 3);
  int aoff[8], boff[NB];
#pragma unroll
  for (int m = 0; m < 8; m++) aoff[m] = (wr * 128 + m * 16 + l15) * BK + eSw;
#pragma unroll
  for (int n = 0; n < NB; n++) boff[n] = (wc * (BNT / 4) + n * 16 + l15) * BK + eSw;

  f32x4 acc[8][NB] = {};

  gll16(&Abuf[0][ldsD0], A + aS0);
  gll16(&Bbuf[0][ldsD0], Bm + bS0);
  gll16(&Abuf[0][ldsD1], A + aS1);
  if constexpr (BNT == 256) gll16(&Bbuf[0][ldsD1], Bm + bS1);
  gll16(&Abuf[1][ldsD0], A + aS0 + BK);
  gll16(&Bbuf[1][ldsD0], Bm + bS0 + BK);
  gll16(&Abuf[1][ldsD1], A + aS1 + BK);
  if constexpr (BNT == 256) gll16(&Bbuf[1][ldsD1], Bm + bS1 + BK);
  if constexpr (BNT == 256)
    asm volatile("s_waitcnt vmcnt(4)" ::: "memory");
  else
    asm volatile("s_waitcnt vmcnt(3)" ::: "memory");
  __builtin_amdgcn_s_barrier();
  asm volatile("" ::: "memory");

  int cur = 0, nxt = 2;
  for (int kt = 0; kt < NT; ++kt) {
    const bf16* __restrict__ Ab = Abuf[cur];
    const bf16* __restrict__ Bb = Bbuf[cur];
    const bool pre = (kt + 2 < NT);
    const size_t k2 = (size_t)(kt + 2) * BK;

    bf16x8 af[8], bq[NB];
#pragma unroll
    for (int m = 0; m < 8; m++) af[m] = *(const bf16x8*)&Ab[aoff[m]];
    bq[0] = *(const bf16x8*)&Bb[boff[0]];
    if constexpr (NB > 2) bq[1] = *(const bf16x8*)&Bb[boff[1]];
    if (pre) {
      gll16(&Abuf[nxt][ldsD0], A + aS0 + k2);
      gll16(&Bbuf[nxt][ldsD0], Bm + bS0 + k2);
    }
    asm volatile("s_waitcnt lgkmcnt(0)" ::: "memory");
    __builtin_amdgcn_sched_barrier(0);
    __builtin_amdgcn_s_setprio(1);
#pragma unroll
    for (int m = 0; m < 8; m++) acc[m][0] = MFMA16(af[m], bq[0], acc[m][0]);
    if constexpr (NB > 2) {
#pragma unroll
      for (int m = 0; m < 8; m++) acc[m][1] = MFMA16(af[m], bq[1], acc[m][1]);
    }
    __builtin_amdgcn_s_setprio(0);

    constexpr int n2 = (NB > 2) ? 2 : 1;
    bf16x8 b2 = *(const bf16x8*)&Bb[boff[n2]];
    bf16x8 b3;
    if constexpr (NB > 2) b3 = *(const bf16x8*)&Bb[boff[3]];
    if (pre) {
      gll16(&Abuf[nxt][ldsD1], A + aS1 + k2);
      if constexpr (BNT == 256) gll16(&Bbuf[nxt][ldsD1], Bm + bS1 + k2);
    }
    asm volatile("s_waitcnt lgkmcnt(0)" ::: "memory");
    __builtin_amdgcn_sched_barrier(0);
    __builtin_amdgcn_s_setprio(1);
#pragma unroll
    for (int m = 0; m < 8; m++) acc[m][n2] = MFMA16(af[m], b2, acc[m][n2]);
    if constexpr (NB > 2) {
#pragma unroll
      for (int m = 0; m < 8; m++) acc[m][3] = MFMA16(af[m], b3, acc[m][3]);
    }
    __builtin_amdgcn_s_setprio(0);

    if (kt < NT - 1) {
      if (pre) {
        if constexpr (BNT == 256)
          asm volatile("s_waitcnt vmcnt(4)" ::: "memory");
        else
          asm volatile("s_waitcnt vmcnt(3)" ::: "memory");
      } else {
        asm volatile("s_waitcnt vmcnt(0)" ::: "memory");
      }
      __builtin_amdgcn_s_barrier();
      asm volatile("" ::: "memory");
    }
    cur = (cur == 2) ? 0 : cur + 1;
    nxt = (nxt == 2) ? 0 : nxt + 1;
  }

  const int grow0 = bm + wr * 128 + (lane >> 4) * 4;
  const int gcol0 = bn + wc * (BNT / 4) + l15;
#pragma unroll
  for (int i = 0; i < 8; i++)
#pragma unroll
    for (int j = 0; j < NB; j++) {
      int grow = grow0 + i * 16;
      int gcol = gcol0 + j * 16;
      if (EPI == 1) {
#pragma unroll
        for (int r = 0; r < 4; r++)
          Cf[(size_t)(grow + r) * 2048 + gcol] = acc[i][j][r];
      } else {
        int mat = gcol >> 11, mcol = gcol & 2047;
        if (mat == 2) {
          int b = grow >> 11;
          bf16x4 pk = {(bf16)acc[i][j][0], (bf16)acc[i][j][1],
                       (bf16)acc[i][j][2], (bf16)acc[i][j][3]};
          *(bf16x4*)&Cvt[((size_t)(b * 2048 + mcol)) * 2048 + (grow & 2047)] = pk;
        } else {
          bf16* Cp = (mat == 0) ? Cq : Ck;
#pragma unroll
          for (int r = 0; r < 4; r++)
            Cp[(size_t)(grow + r) * 2048 + mcol] = (bf16)acc[i][j][r];
        }
      }
    }
}

// ---------------- fused RMSNorm + RoPE for Q and K, one launch -------------
__global__ __launch_bounds__(256) void normrope2_kernel(bf16* __restrict__ Tq,
                                                        bf16* __restrict__ Tk,
                                                        const float* __restrict__ wq,
                                                        const float* __restrict__ wk,
                                                        const float* __restrict__ cs,
                                                        const float* __restrict__ sn) {
  bf16* T = blockIdx.y ? Tk : Tq;
  const float* w = blockIdx.y ? wk : wq;
  int row = blockIdx.x * 4 + (threadIdx.x >> 6);
  int lane = threadIdx.x & 63;
  int bl = row >> 4;
  int h = row & 15;
  bf16* p = T + (size_t)bl * EMB + h * HD;
  float v1 = (float)p[lane];
  float v2 = (float)p[lane + 64];
  float ss = v1 * v1 + v2 * v2;
#pragma unroll
  for (int m = 32; m; m >>= 1) ss += __shfl_xor(ss, m, 64);
  float r = rsqrtf(ss * (1.0f / 128.0f) + 1e-6f);
  float n1 = v1 * r * w[lane];
  float n2 = v2 * r * w[lane + 64];
  float c = cs[(size_t)bl * 64 + lane];
  float s = sn[(size_t)bl * 64 + lane];
  p[lane]      = (bf16)(n1 * c - n2 * s);
  p[lane + 64] = (bf16)(n1 * s + n2 * c);
}

// ---- causal flash attention: swapped QK^T + packed-b64 P writes -----------
// mfma(K,Q) -> lane holds P[k = s*16+grp*4+0..3][q = l15]: 4 consecutive k
// -> one ds_write_b64 per s (vs 16 scalar b16). P read + K=32 PV identical
// to the proven round-13 path. lsum = scalar accum + 2 shfl (no ones-MFMA).
__device__ __forceinline__ void stage_kv(bf16* Ksb, bf16* Vsb,
                                         const bf16* gK, const bf16* gV,
                                         int kt, int w, int lane) {
#pragma unroll
  for (int i = 0; i < 4; i++) {
    int ck = i * 256 + w * 64 + lane;
    int kr = ck >> 4, kc = ck & 15;
    gll16(&Ksb[ck * 8], gK + (size_t)(kt * 64 + kr) * EMB + ((kc ^ (kr & 7)) * 8));
    int dr = ck >> 3, vc = ck & 7;
    gll16(&Vsb[ck * 8], gV + (size_t)dr * L_SEQ + kt * 64 + ((vc ^ (dr & 7)) * 8));
  }
}

__global__ __launch_bounds__(256) void fattn_kernel(const bf16* __restrict__ Q,
                                                    const bf16* __restrict__ K,
                                                    const bf16* __restrict__ Vt,
                                                    bf16* __restrict__ AO) {
  __shared__ bf16 Ks[2][64 * 128];
  __shared__ bf16 Vs[2][64 * 128];
  __shared__ bf16 Ps[4 * 16 * 64];
  const int tid = threadIdx.x, lane = tid & 63, w = tid >> 6;
  const int l15 = lane & 15, grp = lane >> 4;

  int id = blockIdx.x + blockIdx.y * 32;
  int bh = id & 63;
  int qt = 31 - (id >> 6);
  const int b = bh >> 4, h = bh & 15;
  const size_t base = (size_t)b * L_SEQ * EMB + h * HD;
  const bf16* gK = K + base;
  const bf16* gV = Vt + (size_t)(b * NH + h) * HD * L_SEQ;
  const int qrow0 = qt * 64 + w * 16;
  const int q_own = qrow0 + l15;

  const float a_ = 0.08838834764831845f * 1.4426950408889634f;
  const float b_ = 12.0f * 1.4426950408889634f;

  bf16x8 qf[4];
  {
    const bf16* qp = Q + base + (size_t)(qrow0 + l15) * EMB + (grp * 8);
#pragma unroll
    for (int c = 0; c < 4; c++) qf[c] = *(const bf16x8*)(qp + c * 32);
  }

  f32x4 O[8] = {};
  float lsum_p = 0.f;
  bf16* myP = Ps + w * 1024;
  // P write slot: row l15, logical chunk c8 = s*2 + (grp>>1), stored at
  // (c8 ^ (l15&7)), element offset (grp&1)*4  -> matches the b128 read swizzle
  const int pwbase = l15 * 64 + (grp & 1) * 4;
  const int c8base = grp >> 1;

  stage_kv(Ks[0], Vs[0], gK, gV, 0, w, lane);
  asm volatile("s_waitcnt vmcnt(0)" ::: "memory");
  __builtin_amdgcn_s_barrier();
  asm volatile("" ::: "memory");

  for (int kt = 0; kt <= qt; kt++) {
    const int cur = kt & 1;
    if (kt < qt) stage_kv(Ks[cur ^ 1], Vs[cur ^ 1], gK, gV, kt + 1, w, lane);

    // S^T = K Q^T (same LDS reads; operands swapped -- round-10 verified)
    f32x4 st[4] = {};
    __builtin_amdgcn_s_setprio(1);
#pragma unroll
    for (int s = 0; s < 4; s++) {
      int row = s * 16 + l15;
#pragma unroll
      for (int c = 0; c < 4; c++) {
        int swc = (c * 4 + grp) ^ (row & 7);
        bf16x8 kf = *(const bf16x8*)&Ks[cur][row * 128 + swc * 8];
        st[s] = MFMA16(kf, qf[c], st[s]);
      }
    }
    __builtin_amdgcn_s_setprio(0);

    // bounded-exp P: 4 consecutive k in-lane -> packed b64 write
    const bool diag = (kt == qt);
#pragma unroll
    for (int s = 0; s < 4; s++) {
      float e[4];
#pragma unroll
      for (int r = 0; r < 4; r++) {
        int kg = kt * 64 + s * 16 + grp * 4 + r;
        float v = exp2f(st[s][r] * a_ - b_);
        if (diag && kg > q_own) v = 0.f;
        e[r] = v;
        lsum_p += v;
      }
      bf16x4 pk = {(bf16)e[0], (bf16)e[1], (bf16)e[2], (bf16)e[3]};
      int c8 = s * 2 + c8base;
      *(bf16x4*)&myP[pwbase + ((c8 ^ (l15 & 7)) << 3)] = pk;
    }

    // P read + PV: byte-identical to the round-13 proven path
    bf16x8 pf[2];
#pragma unroll
    for (int kk = 0; kk < 2; kk++) {
      int swc = (kk * 4 + grp) ^ (l15 & 7);
      pf[kk] = *(const bf16x8*)&myP[l15 * 64 + swc * 8];
    }
    __builtin_amdgcn_s_setprio(1);
#pragma unroll
    for (int ni = 0; ni < 8; ni++) {
#pragma unroll
      for (int kk = 0; kk < 2; kk++) {
        int drow = ni * 16 + l15;
        int swc = (kk * 4 + grp) ^ (drow & 7);
        bf16x8 vf = *(const bf16x8*)&Vs[cur][drow * 64 + swc * 8];
        O[ni] = MFMA16(pf[kk], vf, O[ni]);
      }
    }
    __builtin_amdgcn_s_setprio(0);

    asm volatile("s_waitcnt vmcnt(0)" ::: "memory");
    __builtin_amdgcn_s_barrier();
    asm volatile("" ::: "memory");
  }

  // row-sum: reduce partials over the 4 grp lanes, then fetch per output row
  lsum_p += __shfl_xor(lsum_p, 16, 64);
  lsum_p += __shfl_xor(lsum_p, 32, 64);
  float lr[4];
#pragma unroll
  for (int r = 0; r < 4; r++) lr[r] = __shfl(lsum_p, grp * 4 + r, 64);

  const int qg0 = qrow0 + grp * 4;
#pragma unroll
  for (int ni = 0; ni < 8; ni++) {
#pragma unroll
    for (int r = 0; r < 4; r++) {
      float o = O[ni][r] / lr[r];
      AO[(size_t)(b * L_SEQ + qg0 + r) * EMB + h * HD + ni * 16 + l15] = (bf16)o;
    }
  }
}

extern "C" void kernel_launch(void* const* d_in, const int* in_sizes, int n_in,
                              void* d_out, int out_size, void* d_ws, size_t ws_size,
                              hipStream_t stream) {
  const float* x = (const float*)d_in[0];
  const float* cosp = (const float*)d_in[2];
  const float* sinp = (const float*)d_in[3];
  const float* Wq = (const float*)d_in[4];
  const float* Wk = (const float*)d_in[5];
  const float* Wv = (const float*)d_in[6];
  const float* Wo = (const float*)d_in[7];
  const float* qw = (const float*)d_in[8];
  const float* kw = (const float*)d_in[9];

  const size_t ACT = (size_t)BLROWS * EMB * sizeof(bf16);
  const size_t WGT = (size_t)EMB * EMB * sizeof(bf16);
  char* ws = (char*)d_ws;
  bf16* xb    = (bf16*)ws;          ws += ACT;
  bf16* WQKVb = (bf16*)ws;          ws += 3 * WGT;
  bf16* Wob   = (bf16*)ws;          ws += WGT;
  bf16* Qb    = (bf16*)ws;          ws += ACT;
  bf16* Kb    = (bf16*)ws;          ws += ACT;
  bf16* Vtb   = (bf16*)ws;          ws += ACT;
  bf16* AOb   = (bf16*)ws;          ws += ACT;

  f2bAll_kernel<<<dim3(512, 5), 256, 0, stream>>>(
      x, Wq, Wk, Wv, Wo, xb, WQKVb, WQKVb + (size_t)EMB * EMB,
      WQKVb + 2 * (size_t)EMB * EMB, Wob, BLROWS * EMB / 4, EMB * EMB / 4);

  gemm256<0, 256><<<768, 512, 0, stream>>>(xb, WQKVb, Qb, Kb, Vtb, nullptr, EMB);

  normrope2_kernel<<<dim3(BLROWS * NH / 4, 2), 256, 0, stream>>>(Qb, Kb, qw, kw,
                                                                 cosp, sinp);

  fattn_kernel<<<dim3(32, B_SZ * NH), 256, 0, stream>>>(Qb, Kb, Vtb, AOb);

  gemm256<1, 128><<<512, 512, 0, stream>>>(AOb, Wob, nullptr, nullptr, nullptr,
                                           (float*)d_out, EMB);
}

// Round 16
// 438.298 us; speedup vs baseline: 1.0747x; 1.0359x over previous
//
#include <hip/hip_runtime.h>
#include <hip/hip_bf16.h>
#include <stdint.h>

#define B_SZ 4
#define L_SEQ 2048
#define EMB 2048
#define NH 16
#define HD 128
#define BLROWS (B_SZ * L_SEQ)   // 8192
#define BK 32

typedef __bf16 bf16;
typedef __bf16 bf16x8 __attribute__((ext_vector_type(8)));
typedef __bf16 bf16x4 __attribute__((ext_vector_type(4)));
typedef float f32x4 __attribute__((ext_vector_type(4)));

#define MFMA16(A, Bv, C) __builtin_amdgcn_mfma_f32_16x16x32_bf16(A, Bv, C, 0, 0, 0)

__device__ __forceinline__ void gll16(bf16* l, const bf16* g) {
  __builtin_amdgcn_global_load_lds(
      (const __attribute__((address_space(1))) unsigned int*)g,
      (__attribute__((address_space(3))) unsigned int*)l, 16, 0, 0);
}

// ---------------- all fp32 -> bf16 conversions, one launch ----------------
__global__ __launch_bounds__(256) void f2bAll_kernel(
    const float* __restrict__ x, const float* __restrict__ w0,
    const float* __restrict__ w1, const float* __restrict__ w2,
    const float* __restrict__ w3, bf16* __restrict__ ox, bf16* __restrict__ o0,
    bf16* __restrict__ o1, bf16* __restrict__ o2, bf16* __restrict__ o3,
    int nx4, int nw4) {
  const int y = blockIdx.y;
  const float* in = (y == 0) ? x : (y == 1) ? w0 : (y == 2) ? w1
                    : (y == 3) ? w2 : w3;
  bf16* out = (y == 0) ? ox : (y == 1) ? o0 : (y == 2) ? o1
              : (y == 3) ? o2 : o3;
  const int n4 = (y == 0) ? nx4 : nw4;
  int i = blockIdx.x * blockDim.x + threadIdx.x;
  int stride = gridDim.x * blockDim.x;
  for (; i < n4; i += stride) {
    float4 v = ((const float4*)in)[i];
    bf16x4 o = {(bf16)v.x, (bf16)v.y, (bf16)v.z, (bf16)v.w};
    ((bf16x4*)out)[i] = o;
  }
}

// ------- 256xBNT GEMM, BK=32, 3-stage counted-vmcnt pipeline ---------------
// Grouped raster: XCD x (bx&7) owns a 4-bm x all-bn rectangle -> per-XCD A
// working set 4MB (L2-resident). (round-11/13 proven: QKV 200us, FETCH 148MB)
template <int EPI, int BNT>
__global__ __launch_bounds__(512, 2) void gemm256(const bf16* __restrict__ A,
                                                  const bf16* __restrict__ Bm,
                                                  bf16* __restrict__ Cq,
                                                  bf16* __restrict__ Ck,
                                                  bf16* __restrict__ Cvt,
                                                  float* __restrict__ Cf,
                                                  int K) {
  constexpr int NB = BNT / 64;
  __shared__ bf16 Abuf[3][256 * BK];
  __shared__ bf16 Bbuf[3][BNT * BK];
  const int tid = threadIdx.x, lane = tid & 63, w = tid >> 6;
  const int wr = w >> 2, wc = w & 3;
  const int l15 = lane & 15;

  const int bx = blockIdx.x;
  const int bm = ((bx & 7) * 4 + ((bx >> 3) & 3)) * 256;
  const int bn = (bx >> 5) * BNT;
  const int NT = K / BK;

  const int idA0 = tid, idA1 = 512 + tid;
  const int ar0 = idA0 >> 2, ar1 = idA1 >> 2;
  const size_t aS0 = (size_t)(bm + ar0) * K + (((idA0 & 3) ^ ((ar0 >> 1) & 3)) * 8);
  const size_t aS1 = (size_t)(bm + ar1) * K + (((idA1 & 3) ^ ((ar1 >> 1) & 3)) * 8);
  const size_t bS0 = (size_t)(bn + ar0) * K + (((idA0 & 3) ^ ((ar0 >> 1) & 3)) * 8);
  const size_t bS1 = (size_t)(bn + ar1) * K + (((idA1 & 3) ^ ((ar1 >> 1) & 3)) * 8);
  const int ldsD0 = idA0 * 8, ldsD1 = idA1 * 8;

  const int eSw = ((lane >> 4) * 8) ^ (((l15 >> 1) & 3) << 3);
  int aoff[8], boff[NB];
#pragma unroll
  for (int m = 0; m < 8; m++) aoff[m] = (wr * 128 + m * 16 + l15) * BK + eSw;
#pragma unroll
  for (int n = 0; n < NB; n++) boff[n] = (wc * (BNT / 4) + n * 16 + l15) * BK + eSw;

  f32x4 acc[8][NB] = {};

  gll16(&Abuf[0][ldsD0], A + aS0);
  gll16(&Bbuf[0][ldsD0], Bm + bS0);
  gll16(&Abuf[0][ldsD1], A + aS1);
  if constexpr (BNT == 256) gll16(&Bbuf[0][ldsD1], Bm + bS1);
  gll16(&Abuf[1][ldsD0], A + aS0 + BK);
  gll16(&Bbuf[1][ldsD0], Bm + bS0 + BK);
  gll16(&Abuf[1][ldsD1], A + aS1 + BK);
  if constexpr (BNT == 256) gll16(&Bbuf[1][ldsD1], Bm + bS1 + BK);
  if constexpr (BNT == 256)
    asm volatile("s_waitcnt vmcnt(4)" ::: "memory");
  else
    asm volatile("s_waitcnt vmcnt(3)" ::: "memory");
  __builtin_amdgcn_s_barrier();
  asm volatile("" ::: "memory");

  int cur = 0, nxt = 2;
  for (int kt = 0; kt < NT; ++kt) {
    const bf16* __restrict__ Ab = Abuf[cur];
    const bf16* __restrict__ Bb = Bbuf[cur];
    const bool pre = (kt + 2 < NT);
    const size_t k2 = (size_t)(kt + 2) * BK;

    bf16x8 af[8], bq[NB];
#pragma unroll
    for (int m = 0; m < 8; m++) af[m] = *(const bf16x8*)&Ab[aoff[m]];
    bq[0] = *(const bf16x8*)&Bb[boff[0]];
    if constexpr (NB > 2) bq[1] = *(const bf16x8*)&Bb[boff[1]];
    if (pre) {
      gll16(&Abuf[nxt][ldsD0], A + aS0 + k2);
      gll16(&Bbuf[nxt][ldsD0], Bm + bS0 + k2);
    }
    asm volatile("s_waitcnt lgkmcnt(0)" ::: "memory");
    __builtin_amdgcn_sched_barrier(0);
    __builtin_amdgcn_s_setprio(1);
#pragma unroll
    for (int m = 0; m < 8; m++) acc[m][0] = MFMA16(af[m], bq[0], acc[m][0]);
    if constexpr (NB > 2) {
#pragma unroll
      for (int m = 0; m < 8; m++) acc[m][1] = MFMA16(af[m], bq[1], acc[m][1]);
    }
    __builtin_amdgcn_s_setprio(0);

    constexpr int n2 = (NB > 2) ? 2 : 1;
    bf16x8 b2 = *(const bf16x8*)&Bb[boff[n2]];
    bf16x8 b3;
    if constexpr (NB > 2) b3 = *(const bf16x8*)&Bb[boff[3]];
    if (pre) {
      gll16(&Abuf[nxt][ldsD1], A + aS1 + k2);
      if constexpr (BNT == 256) gll16(&Bbuf[nxt][ldsD1], Bm + bS1 + k2);
    }
    asm volatile("s_waitcnt lgkmcnt(0)" ::: "memory");
    __builtin_amdgcn_sched_barrier(0);
    __builtin_amdgcn_s_setprio(1);
#pragma unroll
    for (int m = 0; m < 8; m++) acc[m][n2] = MFMA16(af[m], b2, acc[m][n2]);
    if constexpr (NB > 2) {
#pragma unroll
      for (int m = 0; m < 8; m++) acc[m][3] = MFMA16(af[m], b3, acc[m][3]);
    }
    __builtin_amdgcn_s_setprio(0);

    if (kt < NT - 1) {
      if (pre) {
        if constexpr (BNT == 256)
          asm volatile("s_waitcnt vmcnt(4)" ::: "memory");
        else
          asm volatile("s_waitcnt vmcnt(3)" ::: "memory");
      } else {
        asm volatile("s_waitcnt vmcnt(0)" ::: "memory");
      }
      __builtin_amdgcn_s_barrier();
      asm volatile("" ::: "memory");
    }
    cur = (cur == 2) ? 0 : cur + 1;
    nxt = (nxt == 2) ? 0 : nxt + 1;
  }

  const int grow0 = bm + wr * 128 + (lane >> 4) * 4;
  const int gcol0 = bn + wc * (BNT / 4) + l15;
#pragma unroll
  for (int i = 0; i < 8; i++)
#pragma unroll
    for (int j = 0; j < NB; j++) {
      int grow = grow0 + i * 16;
      int gcol = gcol0 + j * 16;
      if (EPI == 1) {
#pragma unroll
        for (int r = 0; r < 4; r++)
          Cf[(size_t)(grow + r) * 2048 + gcol] = acc[i][j][r];
      } else {
        int mat = gcol >> 11, mcol = gcol & 2047;
        if (mat == 2) {
          int b = grow >> 11;
          bf16x4 pk = {(bf16)acc[i][j][0], (bf16)acc[i][j][1],
                       (bf16)acc[i][j][2], (bf16)acc[i][j][3]};
          *(bf16x4*)&Cvt[((size_t)(b * 2048 + mcol)) * 2048 + (grow & 2047)] = pk;
        } else {
          bf16* Cp = (mat == 0) ? Cq : Ck;
#pragma unroll
          for (int r = 0; r < 4; r++)
            Cp[(size_t)(grow + r) * 2048 + mcol] = (bf16)acc[i][j][r];
        }
      }
    }
}

// ---------------- fused RMSNorm + RoPE for Q and K, one launch -------------
__global__ __launch_bounds__(256) void normrope2_kernel(bf16* __restrict__ Tq,
                                                        bf16* __restrict__ Tk,
                                                        const float* __restrict__ wq,
                                                        const float* __restrict__ wk,
                                                        const float* __restrict__ cs,
                                                        const float* __restrict__ sn) {
  bf16* T = blockIdx.y ? Tk : Tq;
  const float* w = blockIdx.y ? wk : wq;
  int row = blockIdx.x * 4 + (threadIdx.x >> 6);
  int lane = threadIdx.x & 63;
  int bl = row >> 4;
  int h = row & 15;
  bf16* p = T + (size_t)bl * EMB + h * HD;
  float v1 = (float)p[lane];
  float v2 = (float)p[lane + 64];
  float ss = v1 * v1 + v2 * v2;
#pragma unroll
  for (int m = 32; m; m >>= 1) ss += __shfl_xor(ss, m, 64);
  float r = rsqrtf(ss * (1.0f / 128.0f) + 1e-6f);
  float n1 = v1 * r * w[lane];
  float n2 = v2 * r * w[lane + 64];
  float c = cs[(size_t)bl * 64 + lane];
  float s = sn[(size_t)bl * 64 + lane];
  p[lane]      = (bf16)(n1 * c - n2 * s);
  p[lane + 64] = (bf16)(n1 * s + n2 * c);
}

// ---- causal flash attention: 8 waves x 128 q-rows, swapped QK^T -----------
// Same per-wave structure as the proven round-15 kernel (16 q-rows/wave,
// swapped mfma(K,Q), packed-b64 P writes, K=32 PV), but one block stages
// each K/V tile for 128 q-rows instead of 64: staging traffic, LDS staging
// writes, and vmcnt/barrier events per unit work drop 1.94x. Waves whose
// rows lie entirely above the k-tile skip compute (wave-uniform gate;
// barriers outside the gate). Causal mask applied unconditionally (cndmask).
__device__ __forceinline__ void stage_kv8(bf16* Ksb, bf16* Vsb,
                                          const bf16* gK, const bf16* gV,
                                          int kt, int tid) {
#pragma unroll
  for (int i = 0; i < 2; i++) {
    int ck = i * 512 + tid;            // 0..1023
    int kr = ck >> 4, kc = ck & 15;
    gll16(&Ksb[ck * 8], gK + (size_t)(kt * 64 + kr) * EMB + ((kc ^ (kr & 7)) * 8));
    int dr = ck >> 3, vc = ck & 7;
    gll16(&Vsb[ck * 8], gV + (size_t)dr * L_SEQ + kt * 64 + ((vc ^ (dr & 7)) * 8));
  }
}

__global__ __launch_bounds__(512, 2) void fattn_kernel(const bf16* __restrict__ Q,
                                                       const bf16* __restrict__ K,
                                                       const bf16* __restrict__ Vt,
                                                       bf16* __restrict__ AO) {
  __shared__ bf16 Ks[2][64 * 128];   // 32 KB
  __shared__ bf16 Vs[2][64 * 128];   // 32 KB
  __shared__ bf16 Ps[8 * 16 * 64];   // 16 KB, wave-private
  const int tid = threadIdx.x, lane = tid & 63, w = tid >> 6;
  const int l15 = lane & 15, grp = lane >> 4;

  int id = blockIdx.x + blockIdx.y * 16;     // grid (16, 64)
  int bh = id & 63;
  int qt = 15 - (id >> 6);                   // heavy q-tiles first
  const int b = bh >> 4, h = bh & 15;
  const size_t base = (size_t)b * L_SEQ * EMB + h * HD;
  const bf16* gK = K + base;
  const bf16* gV = Vt + (size_t)(b * NH + h) * HD * L_SEQ;
  const int qrow0 = qt * 128 + w * 16;       // wave's 16 q-rows
  const int q_own = qrow0 + l15;

  const float a_ = 0.08838834764831845f * 1.4426950408889634f;
  const float b_ = 12.0f * 1.4426950408889634f;

  bf16x8 qf[4];
  {
    const bf16* qp = Q + base + (size_t)(qrow0 + l15) * EMB + (grp * 8);
#pragma unroll
    for (int c = 0; c < 4; c++) qf[c] = *(const bf16x8*)(qp + c * 32);
  }

  f32x4 O[8] = {};
  float lsum_p = 0.f;
  bf16* myP = Ps + w * 1024;
  const int pwbase = l15 * 64 + (grp & 1) * 4;
  const int c8base = grp >> 1;

  const int nkt = 2 * qt + 2;
  stage_kv8(Ks[0], Vs[0], gK, gV, 0, tid);
  asm volatile("s_waitcnt vmcnt(0)" ::: "memory");
  __builtin_amdgcn_s_barrier();
  asm volatile("" ::: "memory");

  for (int kt = 0; kt < nkt; kt++) {
    const int cur = kt & 1;
    if (kt + 1 < nkt) stage_kv8(Ks[cur ^ 1], Vs[cur ^ 1], gK, gV, kt + 1, tid);

    if (kt * 64 <= qrow0 + 15) {   // wave-uniform gate
      // S^T = K Q^T
      f32x4 st[4] = {};
      __builtin_amdgcn_s_setprio(1);
#pragma unroll
      for (int s = 0; s < 4; s++) {
        int row = s * 16 + l15;
#pragma unroll
        for (int c = 0; c < 4; c++) {
          int swc = (c * 4 + grp) ^ (row & 7);
          bf16x8 kf = *(const bf16x8*)&Ks[cur][row * 128 + swc * 8];
          st[s] = MFMA16(kf, qf[c], st[s]);
        }
      }
      __builtin_amdgcn_s_setprio(0);

      // bounded-exp P, packed b64 write (mask always)
#pragma unroll
      for (int s = 0; s < 4; s++) {
        float e[4];
#pragma unroll
        for (int r = 0; r < 4; r++) {
          int kg = kt * 64 + s * 16 + grp * 4 + r;
          float v = exp2f(st[s][r] * a_ - b_);
          if (kg > q_own) v = 0.f;
          e[r] = v;
          lsum_p += v;
        }
        bf16x4 pk = {(bf16)e[0], (bf16)e[1], (bf16)e[2], (bf16)e[3]};
        int c8 = s * 2 + c8base;
        *(bf16x4*)&myP[pwbase + ((c8 ^ (l15 & 7)) << 3)] = pk;
      }

      // P read + PV (round-13 proven path)
      bf16x8 pf[2];
#pragma unroll
      for (int kk = 0; kk < 2; kk++) {
        int swc = (kk * 4 + grp) ^ (l15 & 7);
        pf[kk] = *(const bf16x8*)&myP[l15 * 64 + swc * 8];
      }
      __builtin_amdgcn_s_setprio(1);
#pragma unroll
      for (int ni = 0; ni < 8; ni++) {
#pragma unroll
        for (int kk = 0; kk < 2; kk++) {
          int drow = ni * 16 + l15;
          int swc = (kk * 4 + grp) ^ (drow & 7);
          bf16x8 vf = *(const bf16x8*)&Vs[cur][drow * 64 + swc * 8];
          O[ni] = MFMA16(pf[kk], vf, O[ni]);
        }
      }
      __builtin_amdgcn_s_setprio(0);
    }

    asm volatile("s_waitcnt vmcnt(0)" ::: "memory");
    __builtin_amdgcn_s_barrier();
    asm volatile("" ::: "memory");
  }

  // row-sum: reduce partials over the 4 grp lanes, then fetch per output row
  lsum_p += __shfl_xor(lsum_p, 16, 64);
  lsum_p += __shfl_xor(lsum_p, 32, 64);
  float lr[4];
#pragma unroll
  for (int r = 0; r < 4; r++) lr[r] = __shfl(lsum_p, grp * 4 + r, 64);

  const int qg0 = qrow0 + grp * 4;
#pragma unroll
  for (int ni = 0; ni < 8; ni++) {
#pragma unroll
    for (int r = 0; r < 4; r++) {
      float o = O[ni][r] / lr[r];
      AO[(size_t)(b * L_SEQ + qg0 + r) * EMB + h * HD + ni * 16 + l15] = (bf16)o;
    }
  }
}

extern "C" void kernel_launch(void* const* d_in, const int* in_sizes, int n_in,
                              void* d_out, int out_size, void* d_ws, size_t ws_size,
                              hipStream_t stream) {
  const float* x = (const float*)d_in[0];
  const float* cosp = (const float*)d_in[2];
  const float* sinp = (const float*)d_in[3];
  const float* Wq = (const float*)d_in[4];
  const float* Wk = (const float*)d_in[5];
  const float* Wv = (const float*)d_in[6];
  const float* Wo = (const float*)d_in[7];
  const float* qw = (const float*)d_in[8];
  const float* kw = (const float*)d_in[9];

  const size_t ACT = (size_t)BLROWS * EMB * sizeof(bf16);
  const size_t WGT = (size_t)EMB * EMB * sizeof(bf16);
  char* ws = (char*)d_ws;
  bf16* xb    = (bf16*)ws;          ws += ACT;
  bf16* WQKVb = (bf16*)ws;          ws += 3 * WGT;
  bf16* Wob   = (bf16*)ws;          ws += WGT;
  bf16* Qb    = (bf16*)ws;          ws += ACT;
  bf16* Kb    = (bf16*)ws;          ws += ACT;
  bf16* Vtb   = (bf16*)ws;          ws += ACT;
  bf16* AOb   = (bf16*)ws;          ws += ACT;

  f2bAll_kernel<<<dim3(512, 5), 256, 0, stream>>>(
      x, Wq, Wk, Wv, Wo, xb, WQKVb, WQKVb + (size_t)EMB * EMB,
      WQKVb + 2 * (size_t)EMB * EMB, Wob, BLROWS * EMB / 4, EMB * EMB / 4);

  gemm256<0, 256><<<768, 512, 0, stream>>>(xb, WQKVb, Qb, Kb, Vtb, nullptr, EMB);

  normrope2_kernel<<<dim3(BLROWS * NH / 4, 2), 256, 0, stream>>>(Qb, Kb, qw, kw,
                                                                 cosp, sinp);

  fattn_kernel<<<dim3(16, B_SZ * NH), 512, 0, stream>>>(Qb, Kb, Vtb, AOb);

  gemm256<1, 128><<<512, 512, 0, stream>>>(AOb, Wob, nullptr, nullptr, nullptr,
                                           (float*)d_out, EMB);
}